// Round 2
// baseline (257.472 us; speedup 1.0000x reference)
//
#include <hip/hip_runtime.h>

#define NN 1024
#define FF 64
#define CC 4
#define EE 32768
#define HH 256

// ---- workspace layout (units of 4-byte words) ----
#define OFF_ADENSE 0u         // 4194304 f  (N*N*C), alive until k_edge_mlp
#define OFF_CNT    4194304u   // 4096 i     -- sort scratch, dead after gather
#define OFF_OFFS   4198400u   // 4097 i
#define OFF_CURSOR 4202512u   // 4096 i
#define OFF_SRTS   4206608u   // 131072 i
#define OFF_SRTW   4337680u   // 131072 f
#define OFF_AGG    4468752u   // 262144 f
#define OFF_HID    4194304u   // 262144 f   -- overlays sort scratch (dead by then)
#define OFF_XN     4730896u   // 65536 f
#define OFF_P      4796432u   // 262144 f
#define OFF_Q      5058576u   // 262144 f
// end 5320720 words = 21.3 MB

// ---------------------------------------------------------------------------
// S1: bucket counts per (c, dst)
__global__ __launch_bounds__(256)
void k_count(const int* __restrict__ ei, int* __restrict__ cnt)
{
    unsigned t = blockIdx.x * 256u + threadIdx.x;   // t < C*E
    unsigned e = t & (EE - 1u);
    unsigned c = t >> 15;
    int dst = ei[c * 2 * EE + EE + e];
    atomicAdd(&cnt[c * NN + dst], 1);
}

// S2: exclusive prefix sum over 4096 counts (single block)
__global__ __launch_bounds__(1024)
void k_scan(const int* __restrict__ cnt, int* __restrict__ offs, int* __restrict__ cursor)
{
    __shared__ int sums[1024];
    const int t = threadIdx.x;
    int c0 = cnt[t * 4], c1 = cnt[t * 4 + 1], c2 = cnt[t * 4 + 2], c3 = cnt[t * 4 + 3];
    int s = c0 + c1 + c2 + c3;
    sums[t] = s;
    __syncthreads();
    for (int d = 1; d < 1024; d <<= 1) {
        int v = (t >= d) ? sums[t - d] : 0;
        __syncthreads();
        sums[t] += v;
        __syncthreads();
    }
    int base = sums[t] - s;   // exclusive
    offs[t * 4]     = base;           cursor[t * 4]     = base;
    offs[t * 4 + 1] = base + c0;      cursor[t * 4 + 1] = base + c0;
    offs[t * 4 + 2] = base + c0 + c1; cursor[t * 4 + 2] = base + c0 + c1;
    offs[t * 4 + 3] = base + c0 + c1 + c2; cursor[t * 4 + 3] = base + c0 + c1 + c2;
    if (t == 1023) offs[4096] = sums[1023];
}

// S3: scatter edges into (c,dst)-sorted buckets
__global__ __launch_bounds__(256)
void k_bucket(const int* __restrict__ ei, const float* __restrict__ ew,
              int* __restrict__ cursor, int* __restrict__ srt_src, float* __restrict__ srt_w)
{
    unsigned t = blockIdx.x * 256u + threadIdx.x;
    unsigned e = t & (EE - 1u);
    unsigned c = t >> 15;
    int src = ei[c * 2 * EE + e];
    int dst = ei[c * 2 * EE + EE + e];
    float w = ew[c * EE + e];
    int pos = atomicAdd(&cursor[c * NN + dst], 1);
    srt_src[pos] = src;
    srt_w[pos] = w;
}

// S4: atomic-free gather: one wave per (c,dst), lane = f
__global__ __launch_bounds__(256)
void k_agg_gather(const float* __restrict__ x, const int* __restrict__ offs,
                  const int* __restrict__ srt_src, const float* __restrict__ srt_w,
                  float* __restrict__ agg)
{
    const int g = blockIdx.x * 4 + (threadIdx.x >> 6);   // bucket id = c*N+dst
    const int lane = threadIdx.x & 63;
    const int c = g >> 10, dst = g & 1023;
    const int beg = offs[g], end = offs[g + 1];
    float acc = 0.f;
    for (int k = beg; k < end; ++k) {
        int src = srt_src[k];
        float w = srt_w[k];
        acc += x[src * FF + lane] * w;
    }
    agg[dst * (CC * FF) + c * FF + lane] = acc;   // full overwrite, no memset needed
}

// ---------------------------------------------------------------------------
// dense adjacency: adense[i][j][c] += w  (131k atomics, cheap; dups possible)
__global__ __launch_bounds__(256)
void k_adj_scatter(const int* __restrict__ ei, const float* __restrict__ ew,
                   float* __restrict__ adense)
{
    unsigned t = blockIdx.x * 256u + threadIdx.x;
    unsigned e = t & (EE - 1u);
    unsigned c = t >> 15;
    int i = ei[c * 2 * EE + e];
    int j = ei[c * 2 * EE + EE + e];
    float w = ew[c * EE + e];
    atomicAdd(&adense[(i * NN + j) * CC + c], w);
}

// ---------------------------------------------------------------------------
// hid[n][h] = relu(bn1[h] + sum_k (agg[n][k] + (1+eps)x[n][k&63]) * Wn1[k][h])
// block = 1024 threads (4 nodes x 256 h) -> 4 waves/SIMD
__global__ __launch_bounds__(1024)
void k_node_mlp1(const float* __restrict__ agg, const float* __restrict__ x,
                 const float* __restrict__ Wn1, const float* __restrict__ bn1,
                 const float* __restrict__ epsp, float* __restrict__ hid)
{
    __shared__ float hval[4][256];
    const int tid = threadIdx.x;
    const int nn = tid >> 8, h = tid & 255;
    const int n0 = blockIdx.x * 4;
    const float ope = 1.0f + epsp[0];
    hval[nn][h] = agg[(n0 + nn) * 256 + h] + ope * x[(n0 + nn) * 64 + (h & 63)];
    __syncthreads();
    float acc = bn1[h];
#pragma unroll 8
    for (int k = 0; k < 256; ++k)
        acc += hval[nn][k] * Wn1[k * 256 + h];
    hid[(n0 + nn) * 256 + h] = fmaxf(acc, 0.f);
}

// xn[n][f] = bn2[f] + hid[n][:] @ Wn2[:,f]   block = 512 (8 nodes x 64 f)
__global__ __launch_bounds__(512)
void k_node_mlp2(const float* __restrict__ hid, const float* __restrict__ Wn2,
                 const float* __restrict__ bn2, float* __restrict__ xn)
{
    __shared__ float hl[8][256];
    const int tid = threadIdx.x;
    const int n0 = blockIdx.x * 8;
    for (int u = tid; u < 2048; u += 512) hl[u >> 8][u & 255] = hid[n0 * 256 + u];
    __syncthreads();
    const int nn = tid >> 6, f = tid & 63;
    float acc = bn2[f];
#pragma unroll 8
    for (int k = 0; k < 256; ++k)
        acc += hl[nn][k] * Wn2[k * 64 + f];
    xn[(n0 + nn) * 64 + f] = acc;
}

// P[n][h] = be1[h] + xn[n] @ We1[4:68,h];  Q[n][h] = xn[n] @ We1[68:132,h]
// block = 1024 (4 nodes x 256 h)
__global__ __launch_bounds__(1024)
void k_pq(const float* __restrict__ xn, const float* __restrict__ We1,
          const float* __restrict__ be1, float* __restrict__ P, float* __restrict__ Q)
{
    __shared__ float xl[4][64];
    const int tid = threadIdx.x;
    const int r = tid >> 8, h = tid & 255;
    const int n0 = blockIdx.x * 4;
    if (tid < 256) xl[tid >> 6][tid & 63] = xn[n0 * 64 + tid];
    __syncthreads();
    float p = be1[h], q = 0.f;
#pragma unroll 8
    for (int f = 0; f < 64; ++f) {
        float xv = xl[r][f];
        p += xv * We1[(4 + f) * 256 + h];
        q += xv * We1[(68 + f) * 256 + h];
    }
    P[(n0 + r) * 256 + h] = p;
    Q[(n0 + r) * 256 + h] = q;
}

// ---------------------------------------------------------------------------
// out[i][j][o] = be2[o] + sum_h relu(P[i][h]+Q[j][h]+sum_c a[i][j][c]*We1[c][h]) * We2[h][o]
// 32x32 pair tile, 1024 blocks (4/CU), 256 threads, 2x2 pairs/thread,
// H chunked 4x64 -> LDS 18.5 KB -> 4 waves/SIMD resident.
__global__ __launch_bounds__(256, 4)
void k_edge_mlp(const float* __restrict__ P, const float* __restrict__ Q,
                const float* __restrict__ adense, const float* __restrict__ We1,
                const float* __restrict__ We2, const float* __restrict__ be2,
                float* __restrict__ out)
{
    __shared__ float4 Pl[32 * 16];   // 8 KB: [row][quad ^ ((row>>1)&7)]
    __shared__ float4 Ql[32 * 16];   // 8 KB
    __shared__ float4 W1l[4 * 16];   // 1 KB: We1[c][hc-chunk] quads
    __shared__ float4 W2l[64];       // 1 KB: We2 rows of chunk

    const int tid = threadIdx.x;
    const int tx = tid & 15, ty = tid >> 4;
    const int iBase = blockIdx.y * 32, jBase = blockIdx.x * 32;
    const int psw = ty & 7;   // P-read swizzle (row>>1 == ty)
    const int qsw = tx & 7;   // Q-read swizzle (row>>1 == tx)

    float4 a[2][2], acc[2][2];
#pragma unroll
    for (int ii = 0; ii < 2; ++ii)
#pragma unroll
        for (int jj = 0; jj < 2; ++jj) {
            a[ii][jj] = *(const float4*)(adense +
                ((size_t)(iBase + ty * 2 + ii) * NN + (jBase + tx * 2 + jj)) * 4);
            acc[ii][jj] = make_float4(0.f, 0.f, 0.f, 0.f);
        }

    for (int hc = 0; hc < 4; ++hc) {
        __syncthreads();   // previous chunk's reads done before restaging
#pragma unroll
        for (int u = 0; u < 2; ++u) {
            int idx = tid + u * 256;          // 0..511
            int row = idx >> 4, q = idx & 15;
            int ph = q ^ ((row >> 1) & 7);
            Pl[row * 16 + ph] = *(const float4*)(P + (iBase + row) * 256 + hc * 64 + q * 4);
            Ql[row * 16 + ph] = *(const float4*)(Q + (jBase + row) * 256 + hc * 64 + q * 4);
        }
        if (tid < 64) {
            int c = tid >> 4, q = tid & 15;
            W1l[tid] = *(const float4*)(We1 + c * 256 + hc * 64 + q * 4);
        } else if (tid < 128) {
            int h = tid - 64;
            W2l[h] = *(const float4*)(We2 + (hc * 64 + h) * 4);
        }
        __syncthreads();

        for (int q = 0; q < 16; ++q) {
            float4 p[2], qv[2], w1[4], w2[4];
#pragma unroll
            for (int r = 0; r < 2; ++r) p[r]  = Pl[(ty * 2 + r) * 16 + (q ^ psw)];
#pragma unroll
            for (int r = 0; r < 2; ++r) qv[r] = Ql[(tx * 2 + r) * 16 + (q ^ qsw)];
#pragma unroll
            for (int c = 0; c < 4; ++c) w1[c] = W1l[c * 16 + q];
#pragma unroll
            for (int k = 0; k < 4; ++k) w2[k] = W2l[q * 4 + k];

#pragma unroll
            for (int ii = 0; ii < 2; ++ii) {
#pragma unroll
                for (int jj = 0; jj < 2; ++jj) {
                    const float4 av = a[ii][jj];
                    float s0 = av.x * w1[0].x + av.y * w1[1].x + av.z * w1[2].x + av.w * w1[3].x;
                    float s1 = av.x * w1[0].y + av.y * w1[1].y + av.z * w1[2].y + av.w * w1[3].y;
                    float s2 = av.x * w1[0].z + av.y * w1[1].z + av.z * w1[2].z + av.w * w1[3].z;
                    float s3 = av.x * w1[0].w + av.y * w1[1].w + av.z * w1[2].w + av.w * w1[3].w;
                    float v0 = fmaxf(p[ii].x + qv[jj].x + s0, 0.f);
                    float v1 = fmaxf(p[ii].y + qv[jj].y + s1, 0.f);
                    float v2 = fmaxf(p[ii].z + qv[jj].z + s2, 0.f);
                    float v3 = fmaxf(p[ii].w + qv[jj].w + s3, 0.f);
                    acc[ii][jj].x += v0 * w2[0].x + v1 * w2[1].x + v2 * w2[2].x + v3 * w2[3].x;
                    acc[ii][jj].y += v0 * w2[0].y + v1 * w2[1].y + v2 * w2[2].y + v3 * w2[3].y;
                    acc[ii][jj].z += v0 * w2[0].z + v1 * w2[1].z + v2 * w2[2].z + v3 * w2[3].z;
                    acc[ii][jj].w += v0 * w2[0].w + v1 * w2[1].w + v2 * w2[2].w + v3 * w2[3].w;
                }
            }
        }
    }

    const float4 b2 = *(const float4*)be2;
#pragma unroll
    for (int ii = 0; ii < 2; ++ii)
#pragma unroll
        for (int jj = 0; jj < 2; ++jj) {
            float4 o = acc[ii][jj];
            o.x += b2.x; o.y += b2.y; o.z += b2.z; o.w += b2.w;
            *(float4*)(out + ((size_t)(iBase + ty * 2 + ii) * NN + (jBase + tx * 2 + jj)) * 4) = o;
        }
}

// ---------------------------------------------------------------------------
extern "C" void kernel_launch(void* const* d_in, const int* in_sizes, int n_in,
                              void* d_out, int out_size, void* d_ws, size_t ws_size,
                              hipStream_t stream)
{
    (void)in_sizes; (void)n_in; (void)out_size; (void)ws_size;
    const float* x   = (const float*)d_in[0];
    const int*   ei  = (const int*)d_in[1];
    const float* ew  = (const float*)d_in[2];
    const float* Wn1 = (const float*)d_in[3];
    const float* bn1 = (const float*)d_in[4];
    const float* Wn2 = (const float*)d_in[5];
    const float* bn2 = (const float*)d_in[6];
    const float* We1 = (const float*)d_in[7];
    const float* be1 = (const float*)d_in[8];
    const float* We2 = (const float*)d_in[9];
    const float* be2 = (const float*)d_in[10];
    const float* eps = (const float*)d_in[11];
    float* out = (float*)d_out;

    float* ws = (float*)d_ws;
    float* adense = ws + OFF_ADENSE;
    int*   cnt    = (int*)(ws + OFF_CNT);
    int*   offs   = (int*)(ws + OFF_OFFS);
    int*   cursor = (int*)(ws + OFF_CURSOR);
    int*   srts   = (int*)(ws + OFF_SRTS);
    float* srtw   = ws + OFF_SRTW;
    float* agg    = ws + OFF_AGG;
    float* hid    = ws + OFF_HID;
    float* xn     = ws + OFF_XN;
    float* Pb     = ws + OFF_P;
    float* Qb     = ws + OFF_Q;

    // zero adense + cnt (contiguous)
    hipMemsetAsync(d_ws, 0, (size_t)(4194304 + 4096) * sizeof(float), stream);

    k_count      <<<(CC * EE) / 256, 256, 0, stream>>>(ei, cnt);
    k_scan       <<<1, 1024, 0, stream>>>(cnt, offs, cursor);
    k_bucket     <<<(CC * EE) / 256, 256, 0, stream>>>(ei, ew, cursor, srts, srtw);
    k_adj_scatter<<<(CC * EE) / 256, 256, 0, stream>>>(ei, ew, adense);
    k_agg_gather <<<(CC * NN) / 4, 256, 0, stream>>>(x, offs, srts, srtw, agg);
    k_node_mlp1  <<<NN / 4, 1024, 0, stream>>>(agg, x, Wn1, bn1, eps, hid);
    k_node_mlp2  <<<NN / 8, 512, 0, stream>>>(hid, Wn2, bn2, xn);
    k_pq         <<<NN / 4, 1024, 0, stream>>>(xn, We1, be1, Pb, Qb);

    dim3 g(NN / 32, NN / 32);
    k_edge_mlp<<<g, 256, 0, stream>>>(Pb, Qb, adense, We1, We2, be2, out);
}

// Round 3
// 237.274 us; speedup vs baseline: 1.0851x; 1.0851x over previous
//
#include <hip/hip_runtime.h>

#define NN 1024
#define FF 64
#define CC 4
#define EE 32768
#define HH 256

// ---- workspace layout (units of 4-byte words) ----
#define OFF_ADENSE 0u         // 4194304 f  (N*N*C)
#define OFF_CNT    4194304u   // 4096 i  (memset together with adense)
#define OFF_OFFS   4198400u   // 4097 i
#define OFF_CURSOR 4202512u   // 4096 i
#define OFF_SRTS   4206608u   // 131072 i
#define OFF_SRTW   4337680u   // 131072 f
#define OFF_P      4468752u   // 262144 f
#define OFF_Q      4730896u   // 262144 f
// end 4993040 words = 20.0 MB

// ---------------------------------------------------------------------------
// S1: bucket counts per (c, dst)
__global__ __launch_bounds__(256)
void k_count(const int* __restrict__ ei, int* __restrict__ cnt)
{
    unsigned t = blockIdx.x * 256u + threadIdx.x;   // t < C*E
    unsigned e = t & (EE - 1u);
    unsigned c = t >> 15;
    int dst = ei[c * 2 * EE + EE + e];
    atomicAdd(&cnt[c * NN + dst], 1);
}

// S2: exclusive prefix sum over 4096 counts. 256 threads x 16 counts,
// wave-shfl scan, single barrier.
__global__ __launch_bounds__(256)
void k_scan(const int* __restrict__ cnt, int* __restrict__ offs, int* __restrict__ cursor)
{
    __shared__ int wsum[4];
    const int t = threadIdx.x;
    int c[16];
    int s = 0;
    const int4* cp = (const int4*)(cnt + t * 16);
#pragma unroll
    for (int u = 0; u < 4; ++u) {
        int4 v = cp[u];
        c[u * 4 + 0] = v.x; c[u * 4 + 1] = v.y; c[u * 4 + 2] = v.z; c[u * 4 + 3] = v.w;
        s += v.x + v.y + v.z + v.w;
    }
    int incl = s;
#pragma unroll
    for (int d = 1; d < 64; d <<= 1) {
        int v = __shfl_up(incl, d, 64);
        if ((t & 63) >= d) incl += v;
    }
    const int w = t >> 6;
    if ((t & 63) == 63) wsum[w] = incl;
    __syncthreads();
    int base = incl - s;                    // exclusive within wave
    for (int ww = 0; ww < w; ++ww) base += wsum[ww];
    int run = base;
#pragma unroll
    for (int u = 0; u < 16; ++u) {
        offs[t * 16 + u] = run;
        cursor[t * 16 + u] = run;
        run += c[u];
    }
    if (t == 255) offs[4096] = run;
}

// S3: bucket-scatter edges + dense adjacency atomics (fused edge pass)
__global__ __launch_bounds__(256)
void k_bucket_adj(const int* __restrict__ ei, const float* __restrict__ ew,
                  int* __restrict__ cursor, int* __restrict__ srt_src,
                  float* __restrict__ srt_w, float* __restrict__ adense)
{
    unsigned t = blockIdx.x * 256u + threadIdx.x;
    unsigned e = t & (EE - 1u);
    unsigned c = t >> 15;
    int src = ei[c * 2 * EE + e];
    int dst = ei[c * 2 * EE + EE + e];
    float w = ew[c * EE + e];
    int pos = atomicAdd(&cursor[c * NN + dst], 1);
    srt_src[pos] = src;
    srt_w[pos] = w;
    atomicAdd(&adense[((size_t)src * NN + dst) * CC + c], w);
}

// ---------------------------------------------------------------------------
// Fused node pipeline: gather -> mlp1 -> mlp2 -> P/Q. 4 nodes per 1024-thread
// block; agg/hid/xn live only in LDS.
__global__ __launch_bounds__(1024)
void k_node(const float* __restrict__ x, const int* __restrict__ offs,
            const int* __restrict__ srt_src, const float* __restrict__ srt_w,
            const float* __restrict__ Wn1, const float* __restrict__ bn1,
            const float* __restrict__ Wn2, const float* __restrict__ bn2,
            const float* __restrict__ We1, const float* __restrict__ be1,
            const float* __restrict__ epsp,
            float* __restrict__ P, float* __restrict__ Q)
{
    __shared__ float hval[4][256];
    __shared__ float hidl[4][256];
    __shared__ float part[4][4][64];
    __shared__ float xnl[4][64];
    const int tid = threadIdx.x;
    const int n0 = blockIdx.x * 4;

    // gather: wave w handles bucket (c = w&3, node = n0 + (w>>2)), lane = f
    {
        const int w = tid >> 6, lane = tid & 63;
        const int c = w & 3, nn = w >> 2;
        const int g = c * NN + (n0 + nn);
        const int beg = offs[g], end = offs[g + 1];
        float acc = 0.f;
        for (int k = beg; k < end; ++k)
            acc += x[srt_src[k] * FF + lane] * srt_w[k];
        const float ope = 1.0f + epsp[0];
        hval[nn][c * 64 + lane] = acc + ope * x[(n0 + nn) * FF + lane];
    }
    __syncthreads();

    // mlp1: hid[nn][h] = relu(bn1[h] + sum_k hval[nn][k] * Wn1[k][h])
    {
        const int nn = tid >> 8, h = tid & 255;
        float acc = bn1[h];
#pragma unroll 8
        for (int k = 0; k < 256; ++k)
            acc += hval[nn][k] * Wn1[k * 256 + h];
        hidl[nn][h] = fmaxf(acc, 0.f);
    }
    __syncthreads();

    // mlp2 partials over 4 k-quarters
    {
        const int kq = tid >> 8, nn = (tid >> 6) & 3, f = tid & 63;
        float p = 0.f;
#pragma unroll 8
        for (int k = kq * 64; k < kq * 64 + 64; ++k)
            p += hidl[nn][k] * Wn2[k * 64 + f];
        part[kq][nn][f] = p;
    }
    __syncthreads();
    if (tid < 256) {
        const int nn = tid >> 6, f = tid & 63;
        xnl[nn][f] = bn2[f] + part[0][nn][f] + part[1][nn][f]
                             + part[2][nn][f] + part[3][nn][f];
    }
    __syncthreads();

    // P/Q projection
    {
        const int r = tid >> 8, h = tid & 255;
        float p = be1[h], q = 0.f;
#pragma unroll 8
        for (int f = 0; f < 64; ++f) {
            float xv = xnl[r][f];
            p += xv * We1[(4 + f) * 256 + h];
            q += xv * We1[(68 + f) * 256 + h];
        }
        P[(n0 + r) * 256 + h] = p;
        Q[(n0 + r) * 256 + h] = q;
    }
}

// ---------------------------------------------------------------------------
// out[i][j][o] = be2[o] + sum_h relu(P[i][h]+Q[j][h]+sum_c a[i][j][c]*We1[c][h]) * We2[h][o]
// 32x32 pair tile, 1024 blocks (4/CU), 2x2 pairs/thread, H chunked 4x64.
// Weights read via wave-uniform GLOBAL indices -> scalar loads (s_load),
// keeping the LDS pipe for P/Q only (4 ds_read_b128 per thread-q, was 12).
__global__ __launch_bounds__(256, 4)
void k_edge_mlp(const float* __restrict__ P, const float* __restrict__ Q,
                const float* __restrict__ adense, const float* __restrict__ We1,
                const float* __restrict__ We2, const float* __restrict__ be2,
                float* __restrict__ out)
{
    __shared__ float4 Pl[32 * 16];   // 8 KB: [row][quad ^ ((row>>1)&7)]
    __shared__ float4 Ql[32 * 16];   // 8 KB

    const int tid = threadIdx.x;
    const int tx = tid & 15, ty = tid >> 4;
    const int iBase = blockIdx.y * 32, jBase = blockIdx.x * 32;
    const int psw = ty & 7;
    const int qsw = tx & 7;

    float4 a[2][2], acc[2][2];
#pragma unroll
    for (int ii = 0; ii < 2; ++ii)
#pragma unroll
        for (int jj = 0; jj < 2; ++jj) {
            a[ii][jj] = *(const float4*)(adense +
                ((size_t)(iBase + ty * 2 + ii) * NN + (jBase + tx * 2 + jj)) * 4);
            acc[ii][jj] = make_float4(0.f, 0.f, 0.f, 0.f);
        }

    for (int hc = 0; hc < 4; ++hc) {
        __syncthreads();
#pragma unroll
        for (int u = 0; u < 2; ++u) {
            int idx = tid + u * 256;
            int row = idx >> 4, q = idx & 15;
            int ph = q ^ ((row >> 1) & 7);
            Pl[row * 16 + ph] = *(const float4*)(P + (iBase + row) * 256 + hc * 64 + q * 4);
            Ql[row * 16 + ph] = *(const float4*)(Q + (jBase + row) * 256 + hc * 64 + q * 4);
        }
        __syncthreads();

        for (int q = 0; q < 16; ++q) {
            // wave-uniform weight loads -> scalar pipe
            float4 w1[4], w2[4];
#pragma unroll
            for (int c = 0; c < 4; ++c)
                w1[c] = *(const float4*)(We1 + c * 256 + hc * 64 + q * 4);
#pragma unroll
            for (int k = 0; k < 4; ++k)
                w2[k] = *(const float4*)(We2 + (hc * 64 + q * 4 + k) * 4);

            float4 p[2], qv[2];
#pragma unroll
            for (int r = 0; r < 2; ++r) p[r]  = Pl[(ty * 2 + r) * 16 + (q ^ psw)];
#pragma unroll
            for (int r = 0; r < 2; ++r) qv[r] = Ql[(tx * 2 + r) * 16 + (q ^ qsw)];

#pragma unroll
            for (int ii = 0; ii < 2; ++ii) {
#pragma unroll
                for (int jj = 0; jj < 2; ++jj) {
                    const float4 av = a[ii][jj];
                    float s0 = av.x * w1[0].x + av.y * w1[1].x + av.z * w1[2].x + av.w * w1[3].x;
                    float s1 = av.x * w1[0].y + av.y * w1[1].y + av.z * w1[2].y + av.w * w1[3].y;
                    float s2 = av.x * w1[0].z + av.y * w1[1].z + av.z * w1[2].z + av.w * w1[3].z;
                    float s3 = av.x * w1[0].w + av.y * w1[1].w + av.z * w1[2].w + av.w * w1[3].w;
                    float v0 = fmaxf(p[ii].x + qv[jj].x + s0, 0.f);
                    float v1 = fmaxf(p[ii].y + qv[jj].y + s1, 0.f);
                    float v2 = fmaxf(p[ii].z + qv[jj].z + s2, 0.f);
                    float v3 = fmaxf(p[ii].w + qv[jj].w + s3, 0.f);
                    acc[ii][jj].x += v0 * w2[0].x + v1 * w2[1].x + v2 * w2[2].x + v3 * w2[3].x;
                    acc[ii][jj].y += v0 * w2[0].y + v1 * w2[1].y + v2 * w2[2].y + v3 * w2[3].y;
                    acc[ii][jj].z += v0 * w2[0].z + v1 * w2[1].z + v2 * w2[2].z + v3 * w2[3].z;
                    acc[ii][jj].w += v0 * w2[0].w + v1 * w2[1].w + v2 * w2[2].w + v3 * w2[3].w;
                }
            }
        }
    }

    const float4 b2 = *(const float4*)be2;
#pragma unroll
    for (int ii = 0; ii < 2; ++ii)
#pragma unroll
        for (int jj = 0; jj < 2; ++jj) {
            float4 o = acc[ii][jj];
            o.x += b2.x; o.y += b2.y; o.z += b2.z; o.w += b2.w;
            *(float4*)(out + ((size_t)(iBase + ty * 2 + ii) * NN + (jBase + tx * 2 + jj)) * 4) = o;
        }
}

// ---------------------------------------------------------------------------
extern "C" void kernel_launch(void* const* d_in, const int* in_sizes, int n_in,
                              void* d_out, int out_size, void* d_ws, size_t ws_size,
                              hipStream_t stream)
{
    (void)in_sizes; (void)n_in; (void)out_size; (void)ws_size;
    const float* x   = (const float*)d_in[0];
    const int*   ei  = (const int*)d_in[1];
    const float* ew  = (const float*)d_in[2];
    const float* Wn1 = (const float*)d_in[3];
    const float* bn1 = (const float*)d_in[4];
    const float* Wn2 = (const float*)d_in[5];
    const float* bn2 = (const float*)d_in[6];
    const float* We1 = (const float*)d_in[7];
    const float* be1 = (const float*)d_in[8];
    const float* We2 = (const float*)d_in[9];
    const float* be2 = (const float*)d_in[10];
    const float* eps = (const float*)d_in[11];
    float* out = (float*)d_out;

    float* ws = (float*)d_ws;
    float* adense = ws + OFF_ADENSE;
    int*   cnt    = (int*)(ws + OFF_CNT);
    int*   offs   = (int*)(ws + OFF_OFFS);
    int*   cursor = (int*)(ws + OFF_CURSOR);
    int*   srts   = (int*)(ws + OFF_SRTS);
    float* srtw   = ws + OFF_SRTW;
    float* Pb     = ws + OFF_P;
    float* Qb     = ws + OFF_Q;

    // zero adense + cnt (contiguous)
    hipMemsetAsync(d_ws, 0, (size_t)(4194304 + 4096) * sizeof(float), stream);

    k_count     <<<(CC * EE) / 256, 256, 0, stream>>>(ei, cnt);
    k_scan      <<<1, 256, 0, stream>>>(cnt, offs, cursor);
    k_bucket_adj<<<(CC * EE) / 256, 256, 0, stream>>>(ei, ew, cursor, srts, srtw, adense);
    k_node      <<<NN / 4, 1024, 0, stream>>>(x, offs, srts, srtw,
                                              Wn1, bn1, Wn2, bn2, We1, be1, eps, Pb, Qb);

    dim3 g(NN / 32, NN / 32);
    k_edge_mlp<<<g, 256, 0, stream>>>(Pb, Qb, adense, We1, We2, be2, out);
}